// Round 2
// baseline (300.657 us; speedup 1.0000x reference)
//
#include <hip/hip_runtime.h>

// QDense: out = s * (U X U^H)[:128,:128] / tr + (1-s) * diag(softmax(rand_w))
// B=512, D=256, O=128.
// Two-kernel plan (latency-tolerant streaming):
//   K1: Yt[b][k'][j] = (X * U_sub^H)^T  as bf16 (2048 blocks, 4 waves, no LDS/barriers)
//   K2: sub = U_sub * Y  (+ trace/normalize/blend epilogue), B-operand = Yt rows (contiguous)
// Fallback to the round-1 fused kernel if ws_size is too small for the 67 MB Yt scratch.

typedef __attribute__((ext_vector_type(4))) float f32x4;
typedef __attribute__((ext_vector_type(8))) short bf16x8;
typedef __attribute__((ext_vector_type(4))) short bf16x4;

static __device__ __forceinline__ short f2bf(float f) {
    unsigned u = __float_as_uint(f);
    u += 0x7fffu + ((u >> 16) & 1u);      // RNE
    return (short)(u >> 16);
}

static __device__ __forceinline__ f32x4 mfma16(bf16x8 a, bf16x8 b, f32x4 c) {
    return __builtin_amdgcn_mfma_f32_16x16x32_bf16(a, b, c, 0, 0, 0);
}

static __device__ __forceinline__ bf16x8 pack8(f32x4 a, f32x4 b) {
    bf16x8 r;
    r[0] = f2bf(a[0]); r[1] = f2bf(a[1]); r[2] = f2bf(a[2]); r[3] = f2bf(a[3]);
    r[4] = f2bf(b[0]); r[5] = f2bf(b[1]); r[6] = f2bf(b[2]); r[7] = f2bf(b[3]);
    return r;
}

// ---- prep: convert U rows [0,128) to bf16 (weight is (D,D,2) interleaved) ----
__global__ void qprep_u(const float* __restrict__ wt,
                        short* __restrict__ Ur, short* __restrict__ Ui) {
    int idx = blockIdx.x * 256 + threadIdx.x;         // 0..32767 = j*256+k, j<128
    float2 v = ((const float2*)wt)[idx];
    Ur[idx] = f2bf(v.x);
    Ui[idx] = f2bf(v.y);
}

// ---- prep: p = softmax(rand_w) (128), s = sigmoid(lam) ----
__global__ void qprep_ps(const float* __restrict__ rw, const float* __restrict__ lm,
                         float* __restrict__ pv, float* __restrict__ sv) {
    int t = threadIdx.x;                               // 64 threads
    float w0 = rw[t], w1 = rw[t + 64];
    float m = fmaxf(w0, w1);
    #pragma unroll
    for (int o = 32; o > 0; o >>= 1) m = fmaxf(m, __shfl_xor(m, o));
    float e0 = expf(w0 - m), e1 = expf(w1 - m);
    float ss = e0 + e1;
    #pragma unroll
    for (int o = 32; o > 0; o >>= 1) ss += __shfl_xor(ss, o);
    pv[t] = e0 / ss;
    pv[t + 64] = e1 / ss;
    if (t == 0) sv[0] = 1.f / (1.f + expf(-lm[0]));
}

// ---- K1: Yt = (X * U_sub^H)^T, bf16.  2048 blocks x 256 thr, no LDS. ----
// block = b*4 + (jb/64); wave w owns X rows jb + w*16 .. +16, all 128 k' cols.
__global__ __launch_bounds__(256, 4) void qk1(
    const float* __restrict__ xr, const float* __restrict__ xi,
    const short* __restrict__ Ur, const short* __restrict__ Ui,
    short* __restrict__ Ytr, short* __restrict__ Yti)
{
    const int blk  = blockIdx.x;
    const int b    = blk >> 2;
    const int jb   = (blk & 3) << 6;
    const int tid  = threadIdx.x;
    const int lane = tid & 63;
    const int w    = tid >> 6;           // 0..3
    const int c16  = lane & 15;
    const int g4   = lane >> 4;

    const float* xr_row = xr + ((size_t)b << 16) + (size_t)(jb + w * 16 + c16) * 256 + g4 * 8;
    const float* xi_row = xi + ((size_t)b << 16) + (size_t)(jb + w * 16 + c16) * 256 + g4 * 8;

    f32x4 zero = {0.f, 0.f, 0.f, 0.f};
    f32x4 yR[8], yI[8];
    #pragma unroll
    for (int n = 0; n < 8; ++n) { yR[n] = zero; yI[n] = zero; }

    #pragma unroll 2
    for (int ks = 0; ks < 8; ++ks) {
        f32x4 a0 = *(const f32x4*)(xr_row + ks * 32);
        f32x4 a1 = *(const f32x4*)(xr_row + ks * 32 + 4);
        f32x4 b0 = *(const f32x4*)(xi_row + ks * 32);
        f32x4 b1 = *(const f32x4*)(xi_row + ks * 32 + 4);
        bf16x8 axr = pack8(a0, a1);
        bf16x8 axi = pack8(b0, b1);
        bf16x8 axrn = axr ^ (short)0x8000;

        const short* urk = Ur + ks * 32 + g4 * 8;
        const short* uik = Ui + ks * 32 + g4 * 8;
        #pragma unroll
        for (int nt = 0; nt < 8; ++nt) {
            int j2 = nt * 16 + c16;                    // U row = output col k'
            bf16x8 bur = *(const bf16x8*)(urk + j2 * 256);
            bf16x8 bui = *(const bf16x8*)(uik + j2 * 256);
            // Yr = Xr Ur^T + Xi Ui^T ; Yi = Xi Ur^T - Xr Ui^T
            yR[nt] = mfma16(axr, bur, yR[nt]);
            yR[nt] = mfma16(axi, bui, yR[nt]);
            yI[nt] = mfma16(axi, bur, yI[nt]);
            yI[nt] = mfma16(axrn, bui, yI[nt]);
        }
    }

    // store Y^T: row k' (stride 256 shorts), 4 consecutive j per lane (8 B)
    short* ytr = Ytr + ((size_t)b << 15);
    short* yti = Yti + ((size_t)b << 15);
    const int j0 = jb + w * 16 + g4 * 4;
    #pragma unroll
    for (int nt = 0; nt < 8; ++nt) {
        int kp = nt * 16 + c16;
        bf16x4 pr, pi;
        pr[0] = f2bf(yR[nt][0]); pr[1] = f2bf(yR[nt][1]);
        pr[2] = f2bf(yR[nt][2]); pr[3] = f2bf(yR[nt][3]);
        pi[0] = f2bf(yI[nt][0]); pi[1] = f2bf(yI[nt][1]);
        pi[2] = f2bf(yI[nt][2]); pi[3] = f2bf(yI[nt][3]);
        *(bf16x4*)(ytr + ((size_t)kp << 8) + j0) = pr;
        *(bf16x4*)(yti + ((size_t)kp << 8) + j0) = pi;
    }
}

// ---- K2: sub = U_sub * Y + epilogue.  512 blocks x 512 thr, no LDS staging. ----
__global__ __launch_bounds__(512, 2) void qk2(
    const short* __restrict__ Ur, const short* __restrict__ Ui,
    const short* __restrict__ Ytr, const short* __restrict__ Yti,
    const float* __restrict__ pv, const float* __restrict__ sv,
    float* __restrict__ out)
{
    __shared__ float red[8];
    const int b    = blockIdx.x;
    const int tid  = threadIdx.x;
    const int lane = tid & 63;
    const int w    = tid >> 6;
    const int c16  = lane & 15;
    const int g4   = lane >> 4;
    const int wm   = w >> 2;             // 0..1 row-half
    const int wn   = w & 3;              // 0..3 col-quarter

    const short* ytr = Ytr + ((size_t)b << 15);
    const short* yti = Yti + ((size_t)b << 15);

    f32x4 zero = {0.f, 0.f, 0.f, 0.f};
    f32x4 sR[4][2], sI[4][2];
    #pragma unroll
    for (int m = 0; m < 4; ++m)
        #pragma unroll
        for (int n = 0; n < 2; ++n) { sR[m][n] = zero; sI[m][n] = zero; }

    #pragma unroll 2
    for (int ks = 0; ks < 8; ++ks) {       // contraction over j, 32 per step
        bf16x8 aur[4], aui[4], auin[4];
        #pragma unroll
        for (int mt = 0; mt < 4; ++mt) {
            int i = wm * 64 + mt * 16 + c16;
            const short* pa = Ur + (size_t)i * 256 + ks * 32 + g4 * 8;
            const short* pb = Ui + (size_t)i * 256 + ks * 32 + g4 * 8;
            aur[mt]  = *(const bf16x8*)pa;
            aui[mt]  = *(const bf16x8*)pb;
            auin[mt] = aui[mt] ^ (short)0x8000;
        }
        #pragma unroll
        for (int nt = 0; nt < 2; ++nt) {
            int kp = wn * 32 + nt * 16 + c16;
            const short* pr = ytr + ((size_t)kp << 8) + ks * 32 + g4 * 8;
            const short* pi = yti + ((size_t)kp << 8) + ks * 32 + g4 * 8;
            bf16x8 byr = *(const bf16x8*)pr;
            bf16x8 byi = *(const bf16x8*)pi;
            #pragma unroll
            for (int mt = 0; mt < 4; ++mt) {
                // sub_r = Ur Yr - Ui Yi ; sub_i = Ui Yr + Ur Yi
                sR[mt][nt] = mfma16(aur[mt],  byr, sR[mt][nt]);
                sR[mt][nt] = mfma16(auin[mt], byi, sR[mt][nt]);
                sI[mt][nt] = mfma16(aui[mt],  byr, sI[mt][nt]);
                sI[mt][nt] = mfma16(aur[mt],  byi, sI[mt][nt]);
            }
        }
    }

    // ---------- epilogue: trace, normalize, blend, store ----------
    float loc = 0.f;
    #pragma unroll
    for (int mt = 0; mt < 4; ++mt)
        #pragma unroll
        for (int nt = 0; nt < 2; ++nt) {
            int colc = wn * 32 + nt * 16 + c16;
            #pragma unroll
            for (int r = 0; r < 4; ++r) {
                int row = wm * 64 + mt * 16 + g4 * 4 + r;
                if (row == colc) loc += sR[mt][nt][r];
            }
        }
    #pragma unroll
    for (int o = 32; o > 0; o >>= 1) loc += __shfl_xor(loc, o);
    if (lane == 0) red[w] = loc;
    __syncthreads();
    float tr = red[0] + red[1] + red[2] + red[3] + red[4] + red[5] + red[6] + red[7];

    float s     = sv[0];
    float inv   = s / tr;
    float onems = 1.f - s;
    float* outr = out + (size_t)b * 16384;
    float* outi = out + 8388608 + (size_t)b * 16384;

    #pragma unroll
    for (int mt = 0; mt < 4; ++mt)
        #pragma unroll
        for (int nt = 0; nt < 2; ++nt) {
            int colc = wn * 32 + nt * 16 + c16;
            #pragma unroll
            for (int r = 0; r < 4; ++r) {
                int row = wm * 64 + mt * 16 + g4 * 4 + r;
                float vr = sR[mt][nt][r] * inv;
                if (row == colc) vr += onems * pv[row];
                outr[row * 128 + colc] = vr;
                outi[row * 128 + colc] = sI[mt][nt][r] * inv;
            }
        }
}

// ================== round-1 fused fallback (ws too small) ==================
__global__ __launch_bounds__(512, 2) void qmain(
    const float* __restrict__ xr, const float* __restrict__ xi,
    const short* __restrict__ Ur, const short* __restrict__ Ui,
    const float* __restrict__ pv, const float* __restrict__ sv,
    float* __restrict__ out)
{
    __shared__ __align__(16) char smem[65536];
    const int b    = blockIdx.x;
    const int tid  = threadIdx.x;
    const int lane = tid & 63;
    const int w    = tid >> 6;
    const int c16  = lane & 15;
    const int g4   = lane >> 4;
    const int wm   = w >> 2;
    const int wn   = w & 3;
    const float* xrb = xr + ((size_t)b << 16);
    const float* xib = xi + ((size_t)b << 16);
    f32x4 zero = {0.f, 0.f, 0.f, 0.f};
    f32x4 sR[4][2], sI[4][2];
    #pragma unroll
    for (int m = 0; m < 4; ++m)
        #pragma unroll
        for (int n = 0; n < 2; ++n) { sR[m][n] = zero; sI[m][n] = zero; }
    for (int jt = 0; jt < 256; jt += 128) {
        f32x4 yR[8], yI[8];
        #pragma unroll
        for (int n = 0; n < 8; ++n) { yR[n] = zero; yI[n] = zero; }
        const float* xr_row = xrb + (size_t)(jt + w * 16 + c16) * 256 + g4 * 8;
        const float* xi_row = xib + (size_t)(jt + w * 16 + c16) * 256 + g4 * 8;
        #pragma unroll 2
        for (int ks = 0; ks < 8; ++ks) {
            f32x4 a0 = *(const f32x4*)(xr_row + ks * 32);
            f32x4 a1 = *(const f32x4*)(xr_row + ks * 32 + 4);
            f32x4 b0 = *(const f32x4*)(xi_row + ks * 32);
            f32x4 b1 = *(const f32x4*)(xi_row + ks * 32 + 4);
            bf16x8 axr = pack8(a0, a1);
            bf16x8 axi = pack8(b0, b1);
            bf16x8 axrn = axr ^ (short)0x8000;
            const short* urk = Ur + ks * 32 + g4 * 8;
            const short* uik = Ui + ks * 32 + g4 * 8;
            #pragma unroll
            for (int nt = 0; nt < 8; ++nt) {
                int j2 = nt * 16 + c16;
                bf16x8 bur = *(const bf16x8*)(urk + j2 * 256);
                bf16x8 bui = *(const bf16x8*)(uik + j2 * 256);
                yR[nt] = mfma16(axr, bur, yR[nt]);
                yR[nt] = mfma16(axi, bui, yR[nt]);
                yI[nt] = mfma16(axi, bur, yI[nt]);
                yI[nt] = mfma16(axrn, bui, yI[nt]);
            }
        }
        __syncthreads();
        {
            int wj = (w * 16 + g4 * 4) * 2;
            #pragma unroll
            for (int nt = 0; nt < 8; ++nt) {
                int j2 = nt * 16 + c16;
                int off = j2 * 256 + (wj ^ ((j2 & 7) << 4));
                bf16x4 pr, pi;
                pr[0] = f2bf(yR[nt][0]); pr[1] = f2bf(yR[nt][1]);
                pr[2] = f2bf(yR[nt][2]); pr[3] = f2bf(yR[nt][3]);
                pi[0] = f2bf(yI[nt][0]); pi[1] = f2bf(yI[nt][1]);
                pi[2] = f2bf(yI[nt][2]); pi[3] = f2bf(yI[nt][3]);
                *(bf16x4*)(smem + off)         = pr;
                *(bf16x4*)(smem + 32768 + off) = pi;
            }
        }
        __syncthreads();
        #pragma unroll
        for (int ks2 = 0; ks2 < 4; ++ks2) {
            bf16x8 aur[4], aui[4], auin[4];
            #pragma unroll
            for (int mt = 0; mt < 4; ++mt) {
                int i = wm * 64 + mt * 16 + c16;
                const short* pa = Ur + (size_t)i * 256 + jt + ks2 * 32 + g4 * 8;
                const short* pb = Ui + (size_t)i * 256 + jt + ks2 * 32 + g4 * 8;
                aur[mt]  = *(const bf16x8*)pa;
                aui[mt]  = *(const bf16x8*)pb;
                auin[mt] = aui[mt] ^ (short)0x8000;
            }
            #pragma unroll
            for (int nt = 0; nt < 2; ++nt) {
                int j2 = wn * 32 + nt * 16 + c16;
                int off = j2 * 256 + ((ks2 * 64 + g4 * 16) ^ ((j2 & 7) << 4));
                bf16x8 byr = *(const bf16x8*)(smem + off);
                bf16x8 byi = *(const bf16x8*)(smem + 32768 + off);
                #pragma unroll
                for (int mt = 0; mt < 4; ++mt) {
                    sR[mt][nt] = mfma16(aur[mt],  byr, sR[mt][nt]);
                    sR[mt][nt] = mfma16(auin[mt], byi, sR[mt][nt]);
                    sI[mt][nt] = mfma16(aui[mt],  byr, sI[mt][nt]);
                    sI[mt][nt] = mfma16(aur[mt],  byi, sI[mt][nt]);
                }
            }
        }
    }
    __syncthreads();
    float loc = 0.f;
    #pragma unroll
    for (int mt = 0; mt < 4; ++mt)
        #pragma unroll
        for (int nt = 0; nt < 2; ++nt) {
            int colc = wn * 32 + nt * 16 + c16;
            #pragma unroll
            for (int r = 0; r < 4; ++r) {
                int row = wm * 64 + mt * 16 + g4 * 4 + r;
                if (row == colc) loc += sR[mt][nt][r];
            }
        }
    #pragma unroll
    for (int o = 32; o > 0; o >>= 1) loc += __shfl_xor(loc, o);
    float* red = (float*)smem;
    if (lane == 0) red[w] = loc;
    __syncthreads();
    float tr = red[0] + red[1] + red[2] + red[3] + red[4] + red[5] + red[6] + red[7];
    float s     = sv[0];
    float inv   = s / tr;
    float onems = 1.f - s;
    float* outr = out + (size_t)b * 16384;
    float* outi = out + 8388608 + (size_t)b * 16384;
    #pragma unroll
    for (int mt = 0; mt < 4; ++mt)
        #pragma unroll
        for (int nt = 0; nt < 2; ++nt) {
            int colc = wn * 32 + nt * 16 + c16;
            #pragma unroll
            for (int r = 0; r < 4; ++r) {
                int row = wm * 64 + mt * 16 + g4 * 4 + r;
                float vr = sR[mt][nt][r] * inv;
                if (row == colc) vr += onems * pv[row];
                outr[row * 128 + colc] = vr;
                outi[row * 128 + colc] = sI[mt][nt][r] * inv;
            }
        }
}

extern "C" void kernel_launch(void* const* d_in, const int* in_sizes, int n_in,
                              void* d_out, int out_size, void* d_ws, size_t ws_size,
                              hipStream_t stream) {
    (void)in_sizes; (void)n_in; (void)out_size;
    const float* xr = (const float*)d_in[0];
    const float* xi = (const float*)d_in[1];
    const float* wt = (const float*)d_in[2];
    const float* rw = (const float*)d_in[3];
    const float* lm = (const float*)d_in[4];

    short* Ur = (short*)d_ws;                       // 128*256 bf16 (64 KB)
    short* Ui = Ur + 32768;                         // 64 KB
    float* pv = (float*)((char*)d_ws + 131072);     // 128 f32
    float* sv = pv + 128;                           // 1 f32
    float* o  = (float*)d_out;

    qprep_u<<<dim3(128), dim3(256), 0, stream>>>(wt, Ur, Ui);
    qprep_ps<<<dim3(1), dim3(64), 0, stream>>>(rw, lm, pv, sv);

    const size_t YT_OFF   = 135168;                 // 131072 + 4096 pad
    const size_t YT_BYTES = (size_t)512 * 128 * 256 * 2;  // 33.55 MB each
    if (ws_size >= YT_OFF + 2 * YT_BYTES) {
        short* Ytr = (short*)((char*)d_ws + YT_OFF);
        short* Yti = (short*)((char*)d_ws + YT_OFF + YT_BYTES);
        qk1<<<dim3(2048), dim3(256), 0, stream>>>(xr, xi, Ur, Ui, Ytr, Yti);
        qk2<<<dim3(512), dim3(512), 0, stream>>>(Ur, Ui, Ytr, Yti, pv, sv, o);
    } else {
        qmain<<<dim3(512), dim3(512), 0, stream>>>(xr, xi, Ur, Ui, pv, sv, o);
    }
}

// Round 3
// 213.291 us; speedup vs baseline: 1.4096x; 1.4096x over previous
//
#include <hip/hip_runtime.h>

// QDense: out = s * (U X U^H)[:128,:128] / tr + (1-s) * diag(softmax(rand_w))
// B=512, D=256, O=128.
// Fused kernel, 1024 blocks (batch b = blk>>1, k'-half kh = blk&1), 512 thr.
// Stage A: Y[j, k'half] = X * U_half^H   (U_half staged in swizzled LDS)
// Stage B: sub[:, k'half] = U_sub * Y    (Y^T tile in swizzled LDS, U from global)
// Trace:   tr = trace(X * P), P = U_sub^H U_sub (precomputed, bf16), folded into
//          stage A as 2 extra MFMAs/ks on waves 0..3 (diag extraction at end).

typedef __attribute__((ext_vector_type(4))) float f32x4;
typedef __attribute__((ext_vector_type(8))) short bf16x8;
typedef __attribute__((ext_vector_type(4))) short bf16x4;

static __device__ __forceinline__ short f2bf(float f) {
    unsigned u = __float_as_uint(f);
    u += 0x7fffu + ((u >> 16) & 1u);      // RNE
    return (short)(u >> 16);
}

static __device__ __forceinline__ f32x4 mfma16(bf16x8 a, bf16x8 b, f32x4 c) {
    return __builtin_amdgcn_mfma_f32_16x16x32_bf16(a, b, c, 0, 0, 0);
}

static __device__ __forceinline__ bf16x8 pack8(f32x4 a, f32x4 b) {
    bf16x8 r;
    r[0] = f2bf(a[0]); r[1] = f2bf(a[1]); r[2] = f2bf(a[2]); r[3] = f2bf(a[3]);
    r[4] = f2bf(b[0]); r[5] = f2bf(b[1]); r[6] = f2bf(b[2]); r[7] = f2bf(b[3]);
    return r;
}

// ---- prep: convert U rows [0,128) to bf16 (weight is (D,D,2) interleaved) ----
__global__ void qprep_u(const float* __restrict__ wt,
                        short* __restrict__ Ur, short* __restrict__ Ui) {
    int idx = blockIdx.x * 256 + threadIdx.x;         // j*256+k, j<128
    float2 v = ((const float2*)wt)[idx];
    Ur[idx] = f2bf(v.x);
    Ui[idx] = f2bf(v.y);
}

// ---- prep: p = softmax(rand_w), s = sigmoid(lam) ----
__global__ void qprep_ps(const float* __restrict__ rw, const float* __restrict__ lm,
                         float* __restrict__ pv, float* __restrict__ sv) {
    int t = threadIdx.x;                               // 64 threads
    float w0 = rw[t], w1 = rw[t + 64];
    float m = fmaxf(w0, w1);
    #pragma unroll
    for (int o = 32; o > 0; o >>= 1) m = fmaxf(m, __shfl_xor(m, o));
    float e0 = expf(w0 - m), e1 = expf(w1 - m);
    float ss = e0 + e1;
    #pragma unroll
    for (int o = 32; o > 0; o >>= 1) ss += __shfl_xor(ss, o);
    pv[t] = e0 / ss;
    pv[t + 64] = e1 / ss;
    if (t == 0) sv[0] = 1.f / (1.f + expf(-lm[0]));
}

// ---- prep: Q[j][k] = P[k][j], P = U_sub^H U_sub (f32 source, bf16 out) ----
__global__ void qprep_q(const float* __restrict__ wt,
                        short* __restrict__ Qrb, short* __restrict__ Qib) {
    int j = blockIdx.x;          // 0..255
    int k = threadIdx.x;         // 0..255
    float ar = 0.f, ai = 0.f;
    for (int i = 0; i < 128; ++i) {
        float2 uk = ((const float2*)wt)[i * 256 + k];
        float2 uj = ((const float2*)wt)[i * 256 + j];
        ar += uk.x * uj.x + uk.y * uj.y;   // Re(conj(U[i,k]) U[i,j])
        ai += uk.x * uj.y - uk.y * uj.x;   // Im
    }
    Qrb[j * 256 + k] = f2bf(ar);
    Qib[j * 256 + k] = f2bf(ai);
}

// ---- main fused kernel ----
__global__ __launch_bounds__(512, 2) void qfused(
    const float* __restrict__ xr, const float* __restrict__ xi,
    const short* __restrict__ Urg, const short* __restrict__ Uig,
    const short* __restrict__ Qrb, const short* __restrict__ Qib,
    const float* __restrict__ pv, const float* __restrict__ sv,
    float* __restrict__ out)
{
    // LDS map (80 KB exactly -> 2 blocks/CU):
    // [0,32768):      UldsR  64 rows (k'half) x 512 B, XOR-swizzled
    // [32768,65536):  UldsI
    // [65536,73728):  YtR    64 rows (k'loc) x 128 B (64 j), XOR-swizzled
    // [73728,81920):  YtI    (reused as red[] in epilogue)
    __shared__ __align__(16) char smem[81920];

    const int bx   = blockIdx.x;
    const int b    = bx >> 1;
    const int kh   = bx & 1;
    const int tid  = threadIdx.x;
    const int lane = tid & 63;
    const int w    = tid >> 6;           // 0..7
    const int c16  = lane & 15;
    const int g4   = lane >> 4;          // 0..3

    // ---- stage U-half into swizzled LDS (source-slot permutation) ----
    #pragma unroll
    for (int q = 0; q < 4; ++q) {
        int c    = tid + q * 512;        // 0..2047 chunks of 16 B per plane
        int row  = c >> 5;               // 0..63
        int slot = c & 31;
        int ss   = slot ^ (row & 7);
        const short* sr = Urg + (size_t)(kh * 64 + row) * 256 + ss * 8;
        const short* si = Uig + (size_t)(kh * 64 + row) * 256 + ss * 8;
        *(bf16x8*)(smem + row * 512 + slot * 16)         = *(const bf16x8*)sr;
        *(bf16x8*)(smem + 32768 + row * 512 + slot * 16) = *(const bf16x8*)si;
    }
    __syncthreads();

    const float* xrb = xr + ((size_t)b << 16);
    const float* xib = xi + ((size_t)b << 16);

    const int  ja  = (w & 3) * 16;       // stage A j-row group within jt-step
    const int  kb  = (w >> 2) * 32;      // stage A k'-group
    const int  wm  = w >> 1;             // stage B i-quarter (0..3)
    const int  wn  = w & 1;              // stage B k'-half-of-half (0..1)
    const bool dotr = (w < 4);           // waves 0..3 own the trace

    f32x4 zero = {0.f, 0.f, 0.f, 0.f};
    f32x4 sR[2][2], sI[2][2];
    #pragma unroll
    for (int m = 0; m < 2; ++m)
        #pragma unroll
        for (int n = 0; n < 2; ++n) { sR[m][n] = zero; sI[m][n] = zero; }
    f32x4 tr4 = zero;

    for (int jt = 0; jt < 256; jt += 64) {
        // ---------- stage A: Yt[64 k'loc][64 j] for this jt-step ----------
        f32x4 yR[2], yI[2];
        yR[0] = zero; yR[1] = zero; yI[0] = zero; yI[1] = zero;

        const int jrow = jt + ja + c16;
        const float* xr_row = xrb + (size_t)jrow * 256 + g4 * 8;
        const float* xi_row = xib + (size_t)jrow * 256 + g4 * 8;
        const short* qr_row = Qrb + (size_t)jrow * 256 + g4 * 8;
        const short* qi_row = Qib + (size_t)jrow * 256 + g4 * 8;

        #pragma unroll 2
        for (int ks = 0; ks < 8; ++ks) {
            f32x4 a0 = *(const f32x4*)(xr_row + ks * 32);
            f32x4 a1 = *(const f32x4*)(xr_row + ks * 32 + 4);
            f32x4 b0 = *(const f32x4*)(xi_row + ks * 32);
            f32x4 b1 = *(const f32x4*)(xi_row + ks * 32 + 4);
            bf16x8 axr  = pack8(a0, a1);
            bf16x8 axi  = pack8(b0, b1);
            bf16x8 axrn = axr ^ (short)0x8000;

            #pragma unroll
            for (int nt = 0; nt < 2; ++nt) {
                int kloc = kb + nt * 16 + c16;
                int off  = kloc * 512 + ((ks * 64 + g4 * 16) ^ ((kloc & 7) << 4));
                bf16x8 bur = *(const bf16x8*)(smem + off);
                bf16x8 bui = *(const bf16x8*)(smem + 32768 + off);
                // Yr = Xr Ur^T + Xi Ui^T ; Yi = Xi Ur^T - Xr Ui^T
                yR[nt] = mfma16(axr,  bur, yR[nt]);
                yR[nt] = mfma16(axi,  bui, yR[nt]);
                yI[nt] = mfma16(axi,  bur, yI[nt]);
                yI[nt] = mfma16(axrn, bui, yI[nt]);
            }
            if (dotr) {
                bf16x8 bqr  = *(const bf16x8*)(qr_row + ks * 32);
                bf16x8 bqi  = *(const bf16x8*)(qi_row + ks * 32);
                bf16x8 axin = axi ^ (short)0x8000;
                // tr += Xr.Qr - Xi.Qi  (diag of D extracted at the end)
                tr4 = mfma16(axr,  bqr, tr4);
                tr4 = mfma16(axin, bqi, tr4);
            }
        }

        __syncthreads();   // previous stage-B Yt reads complete

        #pragma unroll
        for (int nt = 0; nt < 2; ++nt) {
            int kloc = kb + nt * 16 + c16;
            int off  = kloc * 128 + (((w & 3) * 32 + g4 * 8) ^ ((kloc & 7) << 4));
            bf16x4 pr, pi;
            pr[0] = f2bf(yR[nt][0]); pr[1] = f2bf(yR[nt][1]);
            pr[2] = f2bf(yR[nt][2]); pr[3] = f2bf(yR[nt][3]);
            pi[0] = f2bf(yI[nt][0]); pi[1] = f2bf(yI[nt][1]);
            pi[2] = f2bf(yI[nt][2]); pi[3] = f2bf(yI[nt][3]);
            *(bf16x4*)(smem + 65536 + off) = pr;
            *(bf16x4*)(smem + 73728 + off) = pi;
        }
        __syncthreads();

        // ---------- stage B: sub[:, kh-half] += U_sub[:, jt..jt+63] * Y ----------
        #pragma unroll
        for (int ks2 = 0; ks2 < 2; ++ks2) {
            bf16x8 aur[2], aui[2], auin[2];
            #pragma unroll
            for (int mt = 0; mt < 2; ++mt) {
                int i = wm * 32 + mt * 16 + c16;
                const short* pa = Urg + (size_t)i * 256 + jt + ks2 * 32 + g4 * 8;
                const short* pb = Uig + (size_t)i * 256 + jt + ks2 * 32 + g4 * 8;
                aur[mt]  = *(const bf16x8*)pa;
                aui[mt]  = *(const bf16x8*)pb;
                auin[mt] = aui[mt] ^ (short)0x8000;
            }
            #pragma unroll
            for (int nt2 = 0; nt2 < 2; ++nt2) {
                int kloc = wn * 32 + nt2 * 16 + c16;
                int off  = kloc * 128 + ((ks2 * 64 + g4 * 16) ^ ((kloc & 7) << 4));
                bf16x8 byr = *(const bf16x8*)(smem + 65536 + off);
                bf16x8 byi = *(const bf16x8*)(smem + 73728 + off);
                #pragma unroll
                for (int mt = 0; mt < 2; ++mt) {
                    // sub_r = Ur Yr - Ui Yi ; sub_i = Ui Yr + Ur Yi
                    sR[mt][nt2] = mfma16(aur[mt],  byr, sR[mt][nt2]);
                    sR[mt][nt2] = mfma16(auin[mt], byi, sR[mt][nt2]);
                    sI[mt][nt2] = mfma16(aui[mt],  byr, sI[mt][nt2]);
                    sI[mt][nt2] = mfma16(aur[mt],  byi, sI[mt][nt2]);
                }
            }
        }
    }

    // ---------- trace: extract diag of tr4 tile, reduce over block ----------
    float loc = (dotr && ((c16 >> 2) == g4)) ? tr4[c16 & 3] : 0.f;
    #pragma unroll
    for (int o = 32; o > 0; o >>= 1) loc += __shfl_xor(loc, o);
    __syncthreads();                       // Yt dead; reuse for reduction
    float* red = (float*)(smem + 65536);
    if (lane == 0) red[w] = loc;           // waves 4..7 contribute 0
    __syncthreads();
    float tr = red[0] + red[1] + red[2] + red[3] + red[4] + red[5] + red[6] + red[7];

    float s     = sv[0];
    float inv   = s / tr;
    float onems = 1.f - s;
    float* outr = out + (size_t)b * 16384;
    float* outi = out + 8388608 + (size_t)b * 16384;

    #pragma unroll
    for (int mt = 0; mt < 2; ++mt)
        #pragma unroll
        for (int nt2 = 0; nt2 < 2; ++nt2) {
            int colc = kh * 64 + wn * 32 + nt2 * 16 + c16;
            #pragma unroll
            for (int r = 0; r < 4; ++r) {
                int row = wm * 32 + mt * 16 + g4 * 4 + r;
                float vr = sR[mt][nt2][r] * inv;
                if (row == colc) vr += onems * pv[row];
                outr[row * 128 + colc] = vr;
                outi[row * 128 + colc] = sI[mt][nt2][r] * inv;
            }
        }
}

extern "C" void kernel_launch(void* const* d_in, const int* in_sizes, int n_in,
                              void* d_out, int out_size, void* d_ws, size_t ws_size,
                              hipStream_t stream) {
    (void)in_sizes; (void)n_in; (void)out_size; (void)ws_size;
    const float* xr = (const float*)d_in[0];
    const float* xi = (const float*)d_in[1];
    const float* wt = (const float*)d_in[2];
    const float* rw = (const float*)d_in[3];
    const float* lm = (const float*)d_in[4];

    short* Ur  = (short*)d_ws;                        // 128x256 bf16 (64 KB)
    short* Ui  = Ur + 32768;                          // 64 KB
    float* pv  = (float*)((char*)d_ws + 131072);      // 128 f32
    float* sv  = pv + 128;                            // 1 f32
    short* Qrb = (short*)((char*)d_ws + 135168);      // 256x256 bf16 (128 KB)
    short* Qib = (short*)((char*)d_ws + 266240);      // 128 KB
    float* o   = (float*)d_out;

    qprep_u<<<dim3(128), dim3(256), 0, stream>>>(wt, Ur, Ui);
    qprep_ps<<<dim3(1), dim3(64), 0, stream>>>(rw, lm, pv, sv);
    qprep_q<<<dim3(256), dim3(256), 0, stream>>>(wt, Qrb, Qib);
    qfused<<<dim3(1024), dim3(512), 0, stream>>>(xr, xi, Ur, Ui, Qrb, Qib, pv, sv, o);
}